// Round 1
// baseline (1499.658 us; speedup 1.0000x reference)
//
#include <hip/hip_runtime.h>
#include <math.h>

#define C 64

__device__ __forceinline__ float sigf(float x) { return 1.0f / (1.0f + __expf(-x)); }

// ---- Kernel 1: W = max(lstm_fwd(conv_w), lstm_bwd(conv_w)) ----------------
// 4096 threads, thread (r,c) computes W[r][c]. Gates: z = x @ W_ih^T + b_ih + b_hh,
// order i,f,g,o; c0=0 so f unused. h = sig(o)*tanh(sig(i)*tanh(g)).
__global__ __launch_bounds__(256) void lstm_w_kernel(
    const float* __restrict__ cw,
    const float* __restrict__ wf, const float* __restrict__ bif, const float* __restrict__ bhf,
    const float* __restrict__ wb, const float* __restrict__ bib, const float* __restrict__ bhb,
    float* __restrict__ W)
{
    int tid = blockIdx.x * blockDim.x + threadIdx.x;   // 0..4095
    int r = tid >> 6, c = tid & 63;
    const float* x = cw + r * C;

    const float* f_i = wf + (0 * C + c) * C;
    const float* f_g = wf + (2 * C + c) * C;
    const float* f_o = wf + (3 * C + c) * C;
    const float* b_i = wb + (0 * C + c) * C;
    const float* b_g = wb + (2 * C + c) * C;
    const float* b_o = wb + (3 * C + c) * C;

    float zif = 0.f, zgf = 0.f, zof = 0.f, zib = 0.f, zgb = 0.f, zob = 0.f;
    #pragma unroll
    for (int k = 0; k < C; ++k) {
        float xv = x[k];
        zif = fmaf(xv, f_i[k], zif);
        zgf = fmaf(xv, f_g[k], zgf);
        zof = fmaf(xv, f_o[k], zof);
        zib = fmaf(xv, b_i[k], zib);
        zgb = fmaf(xv, b_g[k], zgb);
        zob = fmaf(xv, b_o[k], zob);
    }
    zif += bif[0 * C + c] + bhf[0 * C + c];
    zgf += bif[2 * C + c] + bhf[2 * C + c];
    zof += bif[3 * C + c] + bhf[3 * C + c];
    zib += bib[0 * C + c] + bhb[0 * C + c];
    zgb += bib[2 * C + c] + bhb[2 * C + c];
    zob += bib[3 * C + c] + bhb[3 * C + c];

    float cf = sigf(zif) * tanhf(zgf);
    float hf = sigf(zof) * tanhf(cf);
    float cb = sigf(zib) * tanhf(zgb);
    float hb = sigf(zob) * tanhf(cb);
    W[tid] = fmaxf(hf, hb);
}

// ---- Kernel 2: deg accumulation (self-loop folded as +1 later) ------------
__global__ __launch_bounds__(256) void deg_kernel(
    const int* __restrict__ col, const float* __restrict__ ew,
    float* __restrict__ deg, int E)
{
    int e = blockIdx.x * 256 + threadIdx.x;
    if (e < E) unsafeAtomicAdd(&deg[col[e]], ew[e]);
}

// ---- Kernel 3: dinv = rsqrt(deg + 1) in place -----------------------------
__global__ __launch_bounds__(256) void dinv_kernel(float* __restrict__ deg, int N)
{
    int i = blockIdx.x * 256 + threadIdx.x;
    if (i < N) {
        float d = deg[i] + 1.0f;   // self-loop weight 1
        deg[i] = rsqrtf(d);        // d >= 1 > 0 always
    }
}

// ---- Kernel 4: Xw = X @ W  (per block: 4 rows, W staged in LDS) -----------
__global__ __launch_bounds__(256) void gemm_xw_kernel(
    const float* __restrict__ X, const float* __restrict__ W,
    float* __restrict__ Y, int N)
{
    __shared__ float Wl[C * C];
    __shared__ float xl[4][C];
    int tid = threadIdx.x;
    #pragma unroll
    for (int i = 0; i < 16; ++i) Wl[tid + i * 256] = W[tid + i * 256];

    int rr = tid >> 6, c = tid & 63;
    int n = blockIdx.x * 4 + rr;
    if (n < N) xl[rr][c] = X[(size_t)n * C + c];
    __syncthreads();
    if (n >= N) return;

    float s = 0.f;
    #pragma unroll
    for (int k = 0; k < C; ++k) s = fmaf(xl[rr][k], Wl[k * C + c], s);
    Y[(size_t)n * C + c] = s;
}

// ---- Kernel 5: scatter-add messages. 16 threads per edge, float4 each -----
__global__ __launch_bounds__(256) void scatter_kernel(
    const int* __restrict__ row, const int* __restrict__ col,
    const float* __restrict__ ew, const float* __restrict__ dinv,
    const float* __restrict__ Xw, float* __restrict__ Xma, int E)
{
    long long t = (long long)blockIdx.x * 256 + threadIdx.x;
    int e = (int)(t >> 4);
    if (e >= E) return;
    int cg = ((int)t & 15) << 2;

    int r = row[e], c = col[e];
    float norm = dinv[r] * dinv[c] * ew[e];
    const float4 v = *(const float4*)(Xw + (size_t)r * C + cg);
    float* dst = Xma + (size_t)c * C + cg;
    unsafeAtomicAdd(dst + 0, v.x * norm);
    unsafeAtomicAdd(dst + 1, v.y * norm);
    unsafeAtomicAdd(dst + 2, v.z * norm);
    unsafeAtomicAdd(dst + 3, v.w * norm);
}

// ---- Kernel 6: out = (ne + ce + Xma + Xw*dinv^2) @ fW^T + fb --------------
// Self-loop term Xw[n]*dinv[n]^2 folded in here. In-place over Xw (=d_out):
// each block reads only its own 4 rows into LDS before writing them.
__global__ __launch_bounds__(256) void fusion_kernel(
    const float* __restrict__ Xw, const float* __restrict__ Xma,
    const float* __restrict__ ne, const float* __restrict__ ce,
    const float* __restrict__ dinv,
    const float* __restrict__ fW, const float* __restrict__ fb,
    float* __restrict__ out, int N)
{
    __shared__ float Wl[C][C + 1];   // transposed + padded: Wl[k][j] = fW[j*C+k]
    __shared__ float tl[4][C];
    int tid = threadIdx.x;
    #pragma unroll
    for (int i = 0; i < 16; ++i) {
        int idx = tid + i * 256;
        Wl[idx & 63][idx >> 6] = fW[idx];
    }

    int rr = tid >> 6, j = tid & 63;
    int n = blockIdx.x * 4 + rr;
    if (n < N) {
        float di = dinv[n];
        size_t o = (size_t)n * C + j;
        tl[rr][j] = ne[o] + ce[o] + Xma[o] + Xw[o] * di * di;
    }
    __syncthreads();
    if (n >= N) return;

    float s = fb[j];
    #pragma unroll
    for (int k = 0; k < C; ++k) s = fmaf(tl[rr][k], Wl[k][j], s);
    out[(size_t)n * C + j] = s;
}

extern "C" void kernel_launch(void* const* d_in, const int* in_sizes, int n_in,
                              void* d_out, int out_size, void* d_ws, size_t ws_size,
                              hipStream_t stream)
{
    const float* X        = (const float*)d_in[0];
    const int*   ei       = (const int*)d_in[1];
    const float* ew       = (const float*)d_in[2];
    const float* node_emb = (const float*)d_in[3];
    const float* com_emb  = (const float*)d_in[4];
    const float* cw       = (const float*)d_in[5];
    const float* w_ih_f   = (const float*)d_in[6];
    const float* b_ih_f   = (const float*)d_in[7];
    const float* b_hh_f   = (const float*)d_in[8];
    const float* w_ih_b   = (const float*)d_in[9];
    const float* b_ih_b   = (const float*)d_in[10];
    const float* b_hh_b   = (const float*)d_in[11];
    const float* fW       = (const float*)d_in[12];
    const float* fb       = (const float*)d_in[13];
    float* out = (float*)d_out;

    const int N = in_sizes[0] / C;
    const int E = in_sizes[2];
    const int* row = ei;        // edge_index[0]
    const int* col = ei + E;    // edge_index[1]

    float* ws   = (float*)d_ws;
    float* W    = ws;                         // C*C
    float* dinv = ws + C * C;                 // N (deg then dinv in place)
    size_t xma_off = ((size_t)C * C + N + 3) & ~(size_t)3;  // 16B-align
    float* Xma  = ws + xma_off;               // N*C

    hipMemsetAsync(dinv, 0, (size_t)N * sizeof(float), stream);
    hipMemsetAsync(Xma, 0, (size_t)N * C * sizeof(float), stream);

    lstm_w_kernel<<<(C * C) / 256, 256, 0, stream>>>(
        cw, w_ih_f, b_ih_f, b_hh_f, w_ih_b, b_ih_b, b_hh_b, W);

    deg_kernel<<<(E + 255) / 256, 256, 0, stream>>>(col, ew, dinv, E);
    dinv_kernel<<<(N + 255) / 256, 256, 0, stream>>>(dinv, N);

    gemm_xw_kernel<<<(N + 3) / 4, 256, 0, stream>>>(X, W, out, N);

    long long scatter_threads = (long long)E * 16;
    scatter_kernel<<<(int)((scatter_threads + 255) / 256), 256, 0, stream>>>(
        row, col, ew, dinv, out, Xma, E);

    fusion_kernel<<<(N + 3) / 4, 256, 0, stream>>>(
        out, Xma, node_emb, com_emb, dinv, fW, fb, out, N);
}

// Round 2
// 385.328 us; speedup vs baseline: 3.8919x; 3.8919x over previous
//
#include <hip/hip_runtime.h>
#include <math.h>

#define C 64

__device__ __forceinline__ float sigf(float x) { return 1.0f / (1.0f + __expf(-x)); }

// ---- Kernel 1: W = max(lstm_fwd(conv_w), lstm_bwd(conv_w)) ----------------
__global__ __launch_bounds__(256) void lstm_w_kernel(
    const float* __restrict__ cw,
    const float* __restrict__ wf, const float* __restrict__ bif, const float* __restrict__ bhf,
    const float* __restrict__ wb, const float* __restrict__ bib, const float* __restrict__ bhb,
    float* __restrict__ W)
{
    int tid = blockIdx.x * blockDim.x + threadIdx.x;   // 0..4095
    int r = tid >> 6, c = tid & 63;
    const float* x = cw + r * C;

    const float* f_i = wf + (0 * C + c) * C;
    const float* f_g = wf + (2 * C + c) * C;
    const float* f_o = wf + (3 * C + c) * C;
    const float* b_i = wb + (0 * C + c) * C;
    const float* b_g = wb + (2 * C + c) * C;
    const float* b_o = wb + (3 * C + c) * C;

    float zif = 0.f, zgf = 0.f, zof = 0.f, zib = 0.f, zgb = 0.f, zob = 0.f;
    #pragma unroll
    for (int k = 0; k < C; ++k) {
        float xv = x[k];
        zif = fmaf(xv, f_i[k], zif);
        zgf = fmaf(xv, f_g[k], zgf);
        zof = fmaf(xv, f_o[k], zof);
        zib = fmaf(xv, b_i[k], zib);
        zgb = fmaf(xv, b_g[k], zgb);
        zob = fmaf(xv, b_o[k], zob);
    }
    zif += bif[0 * C + c] + bhf[0 * C + c];
    zgf += bif[2 * C + c] + bhf[2 * C + c];
    zof += bif[3 * C + c] + bhf[3 * C + c];
    zib += bib[0 * C + c] + bhb[0 * C + c];
    zgb += bib[2 * C + c] + bhb[2 * C + c];
    zob += bib[3 * C + c] + bhb[3 * C + c];

    float cf = sigf(zif) * tanhf(zgf);
    float hf = sigf(zof) * tanhf(cf);
    float cb = sigf(zib) * tanhf(zgb);
    float hb = sigf(zob) * tanhf(cb);
    W[tid] = fmaxf(hf, hb);
}

// ---- Kernel 2: weighted degree + unweighted count histogram ---------------
__global__ __launch_bounds__(256) void deg_hist_kernel(
    const int* __restrict__ col, const float* __restrict__ ew,
    float* __restrict__ deg, int* __restrict__ cnt, int E)
{
    int e = blockIdx.x * 256 + threadIdx.x;
    if (e < E) {
        int c = col[e];
        unsafeAtomicAdd(&deg[c], ew[e]);
        atomicAdd(&cnt[c], 1);
    }
}

// ---- Kernel 3: dinv = rsqrt(deg + 1) in place -----------------------------
__global__ __launch_bounds__(256) void dinv_kernel(float* __restrict__ deg, int N)
{
    int i = blockIdx.x * 256 + threadIdx.x;
    if (i < N) deg[i] = rsqrtf(deg[i] + 1.0f);   // self-loop weight 1, always > 0
}

// ---- Scan phase A: per-1024-chunk sums ------------------------------------
__global__ __launch_bounds__(256) void scan_partial_kernel(
    const int* __restrict__ cnt, int* __restrict__ partial, int N)
{
    __shared__ int red[256];
    int b = blockIdx.x, t = threadIdx.x;
    int base = b * 1024;
    int s = 0;
    #pragma unroll
    for (int i = 0; i < 4; ++i) {
        int idx = base + t + i * 256;
        s += (idx < N) ? cnt[idx] : 0;
    }
    red[t] = s;
    __syncthreads();
    for (int o = 128; o > 0; o >>= 1) {
        if (t < o) red[t] += red[t + o];
        __syncthreads();
    }
    if (t == 0) partial[b] = red[0];
}

// ---- Scan phase B: exclusive scan of chunk sums (single block) ------------
__global__ __launch_bounds__(256) void scan_spine_kernel(int* __restrict__ partial, int NB)
{
    __shared__ int buf[1024];
    int t = threadIdx.x;
    for (int i = t; i < 1024; i += 256) buf[i] = (i < NB) ? partial[i] : 0;
    __syncthreads();
    if (t == 0) {
        int run = 0;
        for (int i = 0; i < NB; ++i) { int v = buf[i]; buf[i] = run; run += v; }
    }
    __syncthreads();
    for (int i = t; i < NB; i += 256) partial[i] = buf[i];
}

// ---- Scan phase C: off[i] = chunk base + exclusive scan within chunk ------
__global__ __launch_bounds__(256) void scan_final_kernel(
    const int* __restrict__ cnt, const int* __restrict__ partial,
    int* __restrict__ off, int N)
{
    __shared__ int wsum[8];
    int b = blockIdx.x, t = threadIdx.x;
    int base = b * 1024 + t * 4;
    int v[4];
    #pragma unroll
    for (int j = 0; j < 4; ++j) {
        int idx = base + j;
        v[j] = (idx < N) ? cnt[idx] : 0;
    }
    int tsum = v[0] + v[1] + v[2] + v[3];
    int lane = t & 63, wid = t >> 6;
    int x = tsum;
    #pragma unroll
    for (int d = 1; d < 64; d <<= 1) {
        int y = __shfl_up(x, d, 64);
        if (lane >= d) x += y;
    }
    if (lane == 63) wsum[wid] = x;
    __syncthreads();
    if (t == 0) {
        int run = 0;
        for (int w = 0; w < 4; ++w) { int z = wsum[w]; wsum[w] = run; run += z; }
    }
    __syncthreads();
    int run = x - tsum + wsum[wid] + partial[b];
    #pragma unroll
    for (int j = 0; j < 4; ++j) {
        int idx = base + j;
        if (idx < N) off[idx] = run;
        run += v[j];
    }
}

// ---- Kernel 4: CSR build — scatter {row, norm} payload by destination -----
// Consumes off[] as cursors: afterwards off[n] == segment END for node n.
__global__ __launch_bounds__(256) void build_kernel(
    const int* __restrict__ row, const int* __restrict__ col,
    const float* __restrict__ ew, const float* __restrict__ dinv,
    int* __restrict__ off, int2* __restrict__ payload, int E)
{
    int e = blockIdx.x * 256 + threadIdx.x;
    if (e >= E) return;
    int c = col[e], r = row[e];
    float norm = dinv[r] * dinv[c] * ew[e];
    int pos = atomicAdd(&off[c], 1);
    payload[pos] = make_int2(r, __float_as_int(norm));
}

// ---- Kernel 5: Xw = X @ W  (32 rows/block, W staged once) -----------------
__global__ __launch_bounds__(256) void gemm_xw_kernel(
    const float* __restrict__ X, const float* __restrict__ W,
    float* __restrict__ Y, int N)
{
    __shared__ float Wl[C * C];
    __shared__ float xl[32][C];
    int t = threadIdx.x;
    #pragma unroll
    for (int i = 0; i < 4; ++i)
        *(float4*)(Wl + 4 * (t + i * 256)) = *(const float4*)(W + 4 * (t + i * 256));

    int n0 = blockIdx.x * 32;
    #pragma unroll
    for (int i = 0; i < 2; ++i) {
        int idx = t + i * 256;            // 0..511 : (row, float4-group)
        int rr = idx >> 4, cc = (idx & 15) << 2;
        int n = n0 + rr;
        float4 v = (n < N) ? *(const float4*)(X + (size_t)n * C + cc)
                           : make_float4(0.f, 0.f, 0.f, 0.f);
        *(float4*)(&xl[rr][cc]) = v;
    }
    __syncthreads();

    int c = t & 63, rb = (t >> 6) * 8;
    float acc[8] = {0.f, 0.f, 0.f, 0.f, 0.f, 0.f, 0.f, 0.f};
    for (int k = 0; k < C; ++k) {
        float w = Wl[k * C + c];
        #pragma unroll
        for (int q = 0; q < 8; ++q) acc[q] = fmaf(xl[rb + q][k], w, acc[q]);
    }
    #pragma unroll
    for (int q = 0; q < 8; ++q) {
        int n = n0 + rb + q;
        if (n < N) Y[(size_t)n * C + c] = acc[q];
    }
}

// ---- Kernel 6: gather-reduce + self-loop + embeddings ---------------------
// tmp[n] = ne[n] + ce[n] + dinv[n]^2 * Xw[n] + sum_e norm_e * Xw[row_e]
__global__ __launch_bounds__(256) void reduce_kernel(
    const int* __restrict__ off, const int* __restrict__ cnt,
    const int2* __restrict__ payload, const float* __restrict__ Xw,
    const float* __restrict__ ne, const float* __restrict__ ce,
    const float* __restrict__ dinv, float* __restrict__ tmp, int N)
{
    int t = blockIdx.x * 256 + threadIdx.x;
    int n = t >> 4;
    if (n >= N) return;
    int g = (t & 15) << 2;

    int end = off[n];
    int start = end - cnt[n];
    float4 acc = make_float4(0.f, 0.f, 0.f, 0.f);
    for (int p = start; p < end; ++p) {
        int2 pl = payload[p];
        float norm = __int_as_float(pl.y);
        const float4 v = *(const float4*)(Xw + (size_t)pl.x * C + g);
        acc.x = fmaf(v.x, norm, acc.x);
        acc.y = fmaf(v.y, norm, acc.y);
        acc.z = fmaf(v.z, norm, acc.z);
        acc.w = fmaf(v.w, norm, acc.w);
    }
    float di = dinv[n], d2 = di * di;
    size_t o = (size_t)n * C + g;
    const float4 xv = *(const float4*)(Xw + o);
    const float4 nv = *(const float4*)(ne + o);
    const float4 cv = *(const float4*)(ce + o);
    acc.x += nv.x + cv.x + xv.x * d2;
    acc.y += nv.y + cv.y + xv.y * d2;
    acc.z += nv.z + cv.z + xv.z * d2;
    acc.w += nv.w + cv.w + xv.w * d2;
    *(float4*)(tmp + o) = acc;
}

// ---- Kernel 7: out = tmp @ fW^T + fb  (32 rows/block) ---------------------
__global__ __launch_bounds__(256) void fusion_kernel(
    const float* __restrict__ tmp, const float* __restrict__ fW,
    const float* __restrict__ fb, float* __restrict__ out, int N)
{
    __shared__ float Wt[C][C + 1];   // Wt[k][j] = fW[j*C+k]
    __shared__ float tl[32][C];
    int t = threadIdx.x;
    #pragma unroll
    for (int i = 0; i < 16; ++i) {
        int idx = t + i * 256;
        Wt[idx & 63][idx >> 6] = fW[idx];
    }
    int n0 = blockIdx.x * 32;
    #pragma unroll
    for (int i = 0; i < 2; ++i) {
        int idx = t + i * 256;
        int rr = idx >> 4, cc = (idx & 15) << 2;
        int n = n0 + rr;
        float4 v = (n < N) ? *(const float4*)(tmp + (size_t)n * C + cc)
                           : make_float4(0.f, 0.f, 0.f, 0.f);
        *(float4*)(&tl[rr][cc]) = v;
    }
    __syncthreads();

    int j = t & 63, rb = (t >> 6) * 8;
    float bj = fb[j];
    float acc[8] = {bj, bj, bj, bj, bj, bj, bj, bj};
    for (int k = 0; k < C; ++k) {
        float w = Wt[k][j];
        #pragma unroll
        for (int q = 0; q < 8; ++q) acc[q] = fmaf(tl[rb + q][k], w, acc[q]);
    }
    #pragma unroll
    for (int q = 0; q < 8; ++q) {
        int n = n0 + rb + q;
        if (n < N) out[(size_t)n * C + j] = acc[q];
    }
}

extern "C" void kernel_launch(void* const* d_in, const int* in_sizes, int n_in,
                              void* d_out, int out_size, void* d_ws, size_t ws_size,
                              hipStream_t stream)
{
    const float* X        = (const float*)d_in[0];
    const int*   ei       = (const int*)d_in[1];
    const float* ew       = (const float*)d_in[2];
    const float* node_emb = (const float*)d_in[3];
    const float* com_emb  = (const float*)d_in[4];
    const float* cw       = (const float*)d_in[5];
    const float* w_ih_f   = (const float*)d_in[6];
    const float* b_ih_f   = (const float*)d_in[7];
    const float* b_hh_f   = (const float*)d_in[8];
    const float* w_ih_b   = (const float*)d_in[9];
    const float* b_ih_b   = (const float*)d_in[10];
    const float* b_hh_b   = (const float*)d_in[11];
    const float* fW       = (const float*)d_in[12];
    const float* fb       = (const float*)d_in[13];
    float* out = (float*)d_out;

    const int N = in_sizes[0] / C;
    const int E = in_sizes[2];
    const int* row = ei;        // edge_index[0]
    const int* col = ei + E;    // edge_index[1]
    const int NB = (N + 1023) / 1024;   // scan chunks

    // ---- workspace layout (byte offsets, 16B-aligned blocks) ----
    char* wsb = (char*)d_ws;
    size_t o = 0;
    auto alloc = [&](size_t bytes) { void* p = wsb + o; o = (o + bytes + 15) & ~(size_t)15; return p; };
    float* W       = (float*)alloc((size_t)C * C * sizeof(float));   // 16 KB
    float* dinv    = (float*)alloc((size_t)N * sizeof(float));       // 400 KB (deg then dinv)
    int*   cnt     = (int*)  alloc((size_t)N * sizeof(int));         // 400 KB
    int*   off     = (int*)  alloc((size_t)N * sizeof(int));         // 400 KB
    int*   partial = (int*)  alloc(1024 * sizeof(int));              // 4 KB
    int2*  payload = (int2*) alloc((size_t)E * sizeof(int2));        // 12.8 MB
    float* tmp     = (float*)alloc((size_t)N * C * sizeof(float));   // 25.6 MB
    float* Xw      = out;   // d_out holds Xw until fusion overwrites it

    hipMemsetAsync(dinv, 0, (size_t)N * sizeof(float), stream);
    hipMemsetAsync(cnt, 0, (size_t)N * sizeof(int), stream);

    lstm_w_kernel<<<(C * C) / 256, 256, 0, stream>>>(
        cw, w_ih_f, b_ih_f, b_hh_f, w_ih_b, b_ih_b, b_hh_b, W);

    deg_hist_kernel<<<(E + 255) / 256, 256, 0, stream>>>(col, ew, dinv, cnt, E);
    dinv_kernel<<<(N + 255) / 256, 256, 0, stream>>>(dinv, N);

    scan_partial_kernel<<<NB, 256, 0, stream>>>(cnt, partial, N);
    scan_spine_kernel<<<1, 256, 0, stream>>>(partial, NB);
    scan_final_kernel<<<NB, 256, 0, stream>>>(cnt, partial, off, N);

    build_kernel<<<(E + 255) / 256, 256, 0, stream>>>(
        row, col, ew, dinv, off, payload, E);

    gemm_xw_kernel<<<(N + 31) / 32, 256, 0, stream>>>(X, W, Xw, N);

    reduce_kernel<<<(N * 16 + 255) / 256, 256, 0, stream>>>(
        off, cnt, payload, Xw, node_emb, com_emb, dinv, tmp, N);

    fusion_kernel<<<(N + 31) / 32, 256, 0, stream>>>(tmp, fW, fb, out, N);
}